// Round 11
// baseline (73.483 us; speedup 1.0000x reference)
//
#include <hip/hip_runtime.h>
#include <math.h>

// Problem constants
constexpr int LL = 4096;
constexpr int CC = 256;
constexpr int MM = 32768;  // N*L rows

typedef unsigned int u32;
typedef unsigned short u16;
typedef __attribute__((ext_vector_type(8))) short bf16x8;
typedef __attribute__((ext_vector_type(4))) float f32x4;

__device__ __forceinline__ u16 f2b(float f) {   // RNE fp32->bf16
    u32 u = __float_as_uint(f);
    u32 r = (u + 0x7fffu + ((u >> 16) & 1u)) >> 16;
    return (u16)r;
}
__device__ __forceinline__ u32 pack2(float a, float b) {  // RNE pair
    return (u32)f2b(a) | ((u32)f2b(b) << 16);
}

// async global->LDS DMA, 16B per lane; LDS dest = wave-uniform base + lane*16
__device__ __forceinline__ void gl_lds16(const u16* g, u16* l) {
    __builtin_amdgcn_global_load_lds(
        (const __attribute__((address_space(1))) unsigned int*)g,
        (__attribute__((address_space(3))) unsigned int*)l, 16, 0, 0);
}

// ---------------------------------------------------------------------------
// prep_w: bf16 transposed weights. Separate launch: the consumers (proj
// phase, gemm1, gather) must see completed weights; same-kernel prep would
// race (dispatch order undefined, G16).
// ---------------------------------------------------------------------------
__global__ __launch_bounds__(256) void prep_w(
    const float* __restrict__ W_in, const float* __restrict__ W_out,
    const float* __restrict__ W_off, const float* __restrict__ W_mask,
    u16* __restrict__ Wt_in, u16* __restrict__ Wt_out, u16* __restrict__ Wcomb)
{
    const int b = blockIdx.x, t = threadIdx.x;
    if (b < 256) {
        Wt_in[b * 256 + t]  = f2b(W_in[t * 256 + b]);
        Wt_out[b * 256 + t] = f2b(W_out[t * 256 + b]);
    } else {
        const int j = b - 256;  // 0..47
        const float v = (j < 24) ? W_off[t * 24 + j] : W_mask[t * 24 + (j - 24)];
        Wcomb[j * 256 + t] = f2b(v);
    }
}

// ---------------------------------------------------------------------------
// conv_feat_proj: fused conv(K=3)+LN+GELU -> bf16 tile in LDS (XOR-swizzled,
// never touches HBM) -> offset/mask MFMA projection -> softmax -> rec.
// 64-row blocks (512). Conv: wave w owns rows [w*16,+16), 2 adjacent rows
// per iteration (shared neighbor loads, 2 independent LN pipelines).
// Proj: wave reads ONLY its own rows from LDS -> no barrier A->B needed.
// ---------------------------------------------------------------------------
__global__ __launch_bounds__(256) void conv_feat_proj(
    const float* __restrict__ x, const float* __restrict__ cw,
    const float* __restrict__ cbias, const float* __restrict__ lng,
    const float* __restrict__ lnb, const u16* __restrict__ Wcomb,
    const float* __restrict__ boff, const float* __restrict__ bmask,
    uint2* __restrict__ rec)
{
    __shared__ __align__(16) u16 feat[64 * 256];   // 32 KB, swizzled rows
    __shared__ float logit[64 * 50];               // 12.8 KB

    const int t = threadIdx.x;
    const int w = t >> 6, lane = t & 63;
    const int blk = blockIdx.x;
    const size_t row0 = (size_t)blk * 64;
    const int l0 = (blk & 63) * 64;                // l of block's first row

    // ---- Phase A: conv + LN + GELU -> LDS (rows [w*16, w*16+16))
    {
        const int c0 = lane << 2;
        const int rb = w * 16;
        const int lw = l0 + rb;
        const float* xb = x + (row0 + rb) * CC + c0;

        const float cw0[4] = {cw[(c0+0)*3+0], cw[(c0+1)*3+0], cw[(c0+2)*3+0], cw[(c0+3)*3+0]};
        const float cw1[4] = {cw[(c0+0)*3+1], cw[(c0+1)*3+1], cw[(c0+2)*3+1], cw[(c0+3)*3+1]};
        const float cw2[4] = {cw[(c0+0)*3+2], cw[(c0+1)*3+2], cw[(c0+2)*3+2], cw[(c0+3)*3+2]};
        const float cb4[4] = {cbias[c0+0], cbias[c0+1], cbias[c0+2], cbias[c0+3]};
        const float lg4[4] = {lng[c0+0], lng[c0+1], lng[c0+2], lng[c0+3]};
        const float lb4[4] = {lnb[c0+0], lnb[c0+1], lnb[c0+2], lnb[c0+3]};

        const float4 zero = make_float4(0.f, 0.f, 0.f, 0.f);
        float4 prev = (lw > 0) ? *(const float4*)(xb - CC) : zero;
        float4 cur  = *(const float4*)(xb);

#pragma unroll 2
        for (int ii = 0; ii < 8; ++ii) {
            float4 n1 = *(const float4*)(xb + (size_t)(2 * ii + 1) * CC);
            float4 n2 = (lw + 2 * ii + 2 < LL)
                        ? *(const float4*)(xb + (size_t)(2 * ii + 2) * CC) : zero;
            const float pA[4] = {prev.x, prev.y, prev.z, prev.w};
            const float cA[4] = {cur.x, cur.y, cur.z, cur.w};
            const float nA[4] = {n1.x, n1.y, n1.z, n1.w};
            const float nB[4] = {n2.x, n2.y, n2.z, n2.w};

            float yA[4], yB[4];
            float sA = 0.f, qA = 0.f, sB = 0.f, qB = 0.f;
#pragma unroll
            for (int j = 0; j < 4; ++j) {
                float vA = fmaf(pA[j], cw0[j], fmaf(cA[j], cw1[j], fmaf(nA[j], cw2[j], cb4[j])));
                float vB = fmaf(cA[j], cw0[j], fmaf(nA[j], cw1[j], fmaf(nB[j], cw2[j], cb4[j])));
                yA[j] = vA; sA += vA; qA += vA * vA;
                yB[j] = vB; sB += vB; qB += vB * vB;
            }
#pragma unroll
            for (int off = 32; off > 0; off >>= 1) {
                sA += __shfl_xor(sA, off);
                qA += __shfl_xor(qA, off);
                sB += __shfl_xor(sB, off);
                qB += __shfl_xor(qB, off);
            }
            const float muA = sA * (1.f / CC), muB = sB * (1.f / CC);
            const float rsA = rsqrtf(qA * (1.f / CC) - muA * muA + 1e-6f);
            const float rsB = rsqrtf(qB * (1.f / CC) - muB * muB + 1e-6f);

            float vA[4], vB[4];
#pragma unroll
            for (int j = 0; j < 4; ++j) {
                const float tA = (yA[j] - muA) * rsA * lg4[j] + lb4[j];
                const float tB = (yB[j] - muB) * rsB * lg4[j] + lb4[j];
                vA[j] = 0.5f * tA * (1.f + erff(tA * 0.70710678118654752f));
                vB[j] = 0.5f * tB * (1.f + erff(tB * 0.70710678118654752f));
            }
            const int rowA = rb + 2 * ii, rowB = rowA + 1;
            const int adA = (rowA * 512 + c0 * 2) ^ ((rowA & 7) << 4);
            const int adB = (rowB * 512 + c0 * 2) ^ ((rowB & 7) << 4);
            *(uint2*)((char*)feat + adA) = make_uint2(pack2(vA[0], vA[1]), pack2(vA[2], vA[3]));
            *(uint2*)((char*)feat + adB) = make_uint2(pack2(vB[0], vB[1]), pack2(vB[2], vB[3]));
            prev = n1; cur = n2;
        }
    }
    // no barrier: Phase B reads only this wave's own rows (ds ordering
    // within a wave is guaranteed by lgkmcnt)

    // ---- Phase B: projection MFMA -> logits (48 cols per row)
    const int lr = lane & 15, lk8 = (lane >> 4) * 8;
    const int r0 = (lane >> 4) * 4;
    {
        f32x4 pacc[3];
#pragma unroll
        for (int ct = 0; ct < 3; ++ct) pacc[ct] = f32x4{0.f, 0.f, 0.f, 0.f};
        const int arow = w * 16 + lr;
        const int abase = arow * 512;
        const int amask = (arow & 7) << 4;
#pragma unroll
        for (int ks = 0; ks < 8; ++ks) {
            const int ke = ks * 32 + lk8;
            bf16x8 a = *(const bf16x8*)((const char*)feat + ((abase + ke * 2) ^ amask));
#pragma unroll
            for (int ct = 0; ct < 3; ++ct) {
                bf16x8 bfr = *(const bf16x8*)(Wcomb + (size_t)(ct * 16 + lr) * 256 + ke);
                pacc[ct] = __builtin_amdgcn_mfma_f32_16x16x32_bf16(a, bfr, pacc[ct], 0, 0, 0);
            }
        }
#pragma unroll
        for (int ct = 0; ct < 3; ++ct) {
            const int j = ct * 16 + lr;
            const float bj = (j < 24) ? boff[j] : bmask[j - 24];
#pragma unroll
            for (int r4 = 0; r4 < 4; ++r4)
                logit[(w * 16 + r0 + r4) * 50 + j] = pacc[ct][r4] + bj;
        }
    }
    __syncthreads();   // Phase C reads logits across waves

    // ---- Phase C: softmax over K + locations -> global records
#pragma unroll
    for (int pi = 0; pi < 2; ++pi) {
        const int pp = pi * 256 + t;        // 0..511
        const int rw = pp >> 3, g = pp & 7;
        const float* lp = &logit[rw * 50];
        const float m0v = lp[24 + g * 3 + 0];
        const float m1v = lp[24 + g * 3 + 1];
        const float m2v = lp[24 + g * 3 + 2];
        const float mx = fmaxf(m0v, fmaxf(m1v, m2v));
        const float e0 = expf(m0v - mx), e1 = expf(m1v - mx), e2 = expf(m2v - mx);
        const float inv = 1.f / (e0 + e1 + e2);
        const float msk[3] = {e0 * inv, e1 * inv, e2 * inv};
        const float lf = (float)(l0 + rw);
        uint2* rbase = rec + row0 * 24 + pp * 3;
#pragma unroll
        for (int k = 0; k < 3; ++k) {
            const float loc = lf + (float)(k - 1) + lp[g * 3 + k];
            float r = fmodf(loc, (float)LL);
            if (r < 0.f) r += (float)LL;
            const float f0 = floorf(r);
            int i0 = (int)f0;
            i0 = i0 < 0 ? 0 : (i0 > LL - 1 ? LL - 1 : i0);
            const int i1 = i0 + 1;
            const float w1 = r - f0;
            const bool valid = (i1 < LL);
            union { u32 uw; _Float16 h[2]; } uh;
            uh.h[0] = (_Float16)(msk[k] * (1.f - w1));
            uh.h[1] = (_Float16)(valid ? msk[k] * w1 : 0.f);
            const u32 ij = (u32)i0 | ((u32)(valid ? i1 : 0) << 16);
            rbase[k] = make_uint2(uh.uw, ij);
        }
    }
}

// ---------------------------------------------------------------------------
// gemm1: x_proj = bf16(x) @ Wt_in^T + b_in (bf16 out), m97 structure:
// 128x128 tile, BK=32, 4 waves, double-buffered LDS. A reg-staged from fp32
// (load-early/write-late); B via global_load_lds. XCD-swizzled blockIdx.
// ---------------------------------------------------------------------------
__global__ __launch_bounds__(256, 2) void gemm1(
    const float* __restrict__ x, const u16* __restrict__ Wt_in,
    const float* __restrict__ b_in, u16* __restrict__ xprojb)
{
    __shared__ u16 As[2][128 * 32];
    __shared__ u16 Bs[2][128 * 32];

    const int t = threadIdx.x;
    const int w = t >> 6, lane = t & 63;
    const int lr = lane & 15, lk = lane >> 4;
    const int wm = w >> 1, wn = w & 1;

    const int d = blockIdx.x;              // 0..511
    const int m_t = (d & 7) * 32 + (d >> 4);
    const int n_t = (d >> 3) & 1;
    const int m0 = m_t * 128, n0 = n_t * 128;

    const int srow = lane >> 2;
    const int scol = (lane & 3) * 8;       // k elements
    const int arow = t >> 1;
    const int akh = (t & 1) * 16;

    f32x4 acc[4][4];
#pragma unroll
    for (int i = 0; i < 4; ++i)
#pragma unroll
        for (int j = 0; j < 4; ++j) acc[i][j] = f32x4{0.f, 0.f, 0.f, 0.f};

    auto STAGE_B = [&](int buf, int kt) {
        const int k0 = kt * 32;
#pragma unroll
        for (int j = 0; j < 2; ++j) {
            const int rr = (w * 2 + j) * 16 + srow;
            gl_lds16(Wt_in + ((size_t)(n0 + rr) << 8) + k0 + scol,
                     &Bs[buf][0] + (w * 2 + j) * 512);
        }
    };
    const float* Abase = x + (size_t)(m0 + arow) * 256 + akh;

    {
        float4 f0 = *(const float4*)(Abase);
        float4 f1 = *(const float4*)(Abase + 4);
        float4 f2 = *(const float4*)(Abase + 8);
        float4 f3 = *(const float4*)(Abase + 12);
        STAGE_B(0, 0);
        u16* dst = &As[0][arow * 32 + akh];
        ((u32*)dst)[0] = pack2(f0.x, f0.y); ((u32*)dst)[1] = pack2(f0.z, f0.w);
        ((u32*)dst)[2] = pack2(f1.x, f1.y); ((u32*)dst)[3] = pack2(f1.z, f1.w);
        ((u32*)dst)[4] = pack2(f2.x, f2.y); ((u32*)dst)[5] = pack2(f2.z, f2.w);
        ((u32*)dst)[6] = pack2(f3.x, f3.y); ((u32*)dst)[7] = pack2(f3.z, f3.w);
    }

#pragma unroll
    for (int kt = 0; kt < 8; ++kt) {
        const int cur = kt & 1;
        __syncthreads();                    // stage of buf[cur] complete
        float4 f0, f1, f2, f3;
        if (kt < 7) {                       // issue next-tile loads EARLY
            const float* ap = Abase + (kt + 1) * 32;
            f0 = *(const float4*)(ap);
            f1 = *(const float4*)(ap + 4);
            f2 = *(const float4*)(ap + 8);
            f3 = *(const float4*)(ap + 12);
            STAGE_B(cur ^ 1, kt + 1);
        }
        bf16x8 af[4], bfr[4];
#pragma unroll
        for (int mt = 0; mt < 4; ++mt)
            af[mt] = *(const bf16x8*)&As[cur][(wm * 64 + mt * 16 + lr) * 32 + lk * 8];
#pragma unroll
        for (int nt = 0; nt < 4; ++nt)
            bfr[nt] = *(const bf16x8*)&Bs[cur][(wn * 64 + nt * 16 + lr) * 32 + lk * 8];
#pragma unroll
        for (int mt = 0; mt < 4; ++mt)
#pragma unroll
            for (int nt = 0; nt < 4; ++nt)
                acc[mt][nt] = __builtin_amdgcn_mfma_f32_16x16x32_bf16(
                    af[mt], bfr[nt], acc[mt][nt], 0, 0, 0);
        if (kt < 7) {                       // write LATE (after MFMAs)
            u16* dst = &As[cur ^ 1][arow * 32 + akh];
            ((u32*)dst)[0] = pack2(f0.x, f0.y); ((u32*)dst)[1] = pack2(f0.z, f0.w);
            ((u32*)dst)[2] = pack2(f1.x, f1.y); ((u32*)dst)[3] = pack2(f1.z, f1.w);
            ((u32*)dst)[4] = pack2(f2.x, f2.y); ((u32*)dst)[5] = pack2(f2.z, f2.w);
            ((u32*)dst)[6] = pack2(f3.x, f3.y); ((u32*)dst)[7] = pack2(f3.z, f3.w);
        }
    }

    const int r0 = lk * 4;
#pragma unroll
    for (int nt = 0; nt < 4; ++nt) {
        const int cn = n0 + wn * 64 + nt * 16 + lr;
        const float bv = b_in[cn];
#pragma unroll
        for (int mt = 0; mt < 4; ++mt)
#pragma unroll
            for (int r4 = 0; r4 < 4; ++r4)
                xprojb[(size_t)(m0 + wm * 64 + mt * 16 + r0 + r4) * 256 + cn] =
                    f2b(acc[mt][nt][r4] + bv);
    }
}

// ---------------------------------------------------------------------------
// gather_gemm: bilinear gather (from records) -> LDS tile -> final GEMM.
// 32-row blocks (1024). LDS = 16KB tile + 6KB records = 22KB.
// ---------------------------------------------------------------------------
__global__ __launch_bounds__(256, 4) void gather_gemm(
    const uint2* __restrict__ rec, const u16* __restrict__ xprojb,
    const u16* __restrict__ Wt_out, const float* __restrict__ b_out,
    float* __restrict__ out)
{
    __shared__ __align__(16) char s_mem[16384];   // 32x256 bf16 tile (swizzled)
    __shared__ uint2 s_pack[768];                 // 6KB records

    const int t = threadIdx.x;
    const int w = t >> 6, lane = t & 63;
    const int lr = lane & 15, lk8 = (lane >> 4) * 8;
    const int r0 = (lane >> 4) * 4;
    const int blk = blockIdx.x;
    const size_t row0 = (size_t)blk * 32;

    // --- load records for our 32 rows (768 uint2, coalesced)
    {
        const uint2* rb = rec + row0 * 24;
#pragma unroll
        for (int e = 0; e < 3; ++e) s_pack[t * 3 + e] = rb[t * 3 + e];
    }
    __syncthreads();

    // --- gather-accumulate -> sampled bf16 tile in LDS (swizzled).
    {
        const int ig = t >> 5, tc = t & 31;
        const int c0 = tc * 8, g4 = tc >> 2;
        const u16* xpn = xprojb + (size_t)(blk >> 7) * LL * 256;
        const int ibeg = ig * 4;
#pragma unroll
        for (int i = ibeg; i < ibeg + 4; ++i) {
            const int bidx = (i * 8 + g4) * 3;
            float v[8] = {0.f, 0.f, 0.f, 0.f, 0.f, 0.f, 0.f, 0.f};
#pragma unroll
            for (int k = 0; k < 3; ++k) {
                const uint2 pk = s_pack[bidx + k];
                union { u32 uw; _Float16 h[2]; } uh; uh.uw = pk.x;
                const float wa = (float)uh.h[0], wb = (float)uh.h[1];
                const int i0 = (int)(pk.y & 0xffffu), i1 = (int)(pk.y >> 16);
                uint4 ua = *(const uint4*)(xpn + (size_t)i0 * 256 + c0);
                uint4 ub = *(const uint4*)(xpn + (size_t)i1 * 256 + c0);
                const u32 au[4] = {ua.x, ua.y, ua.z, ua.w};
                const u32 bu[4] = {ub.x, ub.y, ub.z, ub.w};
#pragma unroll
                for (int j = 0; j < 4; ++j) {
                    v[2 * j]     = fmaf(wa, __uint_as_float(au[j] << 16),
                                   fmaf(wb, __uint_as_float(bu[j] << 16), v[2 * j]));
                    v[2 * j + 1] = fmaf(wa, __uint_as_float(au[j] & 0xffff0000u),
                                   fmaf(wb, __uint_as_float(bu[j] & 0xffff0000u), v[2 * j + 1]));
                }
            }
            uint4 wd;
            wd.x = pack2(v[0], v[1]); wd.y = pack2(v[2], v[3]);
            wd.z = pack2(v[4], v[5]); wd.w = pack2(v[6], v[7]);
            const int addr = (i * 512 + tc * 16) ^ ((i & 7) << 4);
            *(uint4*)(s_mem + addr) = wd;
        }
    }
    __syncthreads();

    // --- final GEMM 32x256 from LDS tile, wave w -> cols [w*64,+64)
    f32x4 acc[2][4];
#pragma unroll
    for (int i = 0; i < 2; ++i)
#pragma unroll
        for (int j = 0; j < 4; ++j) acc[i][j] = f32x4{0.f, 0.f, 0.f, 0.f};

    const u16* Bw = Wt_out + (size_t)(w * 64) * 256;
#pragma unroll
    for (int ks = 0; ks < 8; ++ks) {
        bf16x8 af[2], bfr[4];
#pragma unroll
        for (int mt = 0; mt < 2; ++mt) {
            const int rm = mt * 16 + lr;
            const int addr = (rm * 512 + ks * 64 + lk8 * 2) ^ ((rm & 7) << 4);
            af[mt] = *(const bf16x8*)(s_mem + addr);
        }
        const int ke = ks * 32 + lk8;
#pragma unroll
        for (int nt = 0; nt < 4; ++nt)
            bfr[nt] = *(const bf16x8*)(Bw + (size_t)(nt * 16 + lr) * 256 + ke);
#pragma unroll
        for (int mt = 0; mt < 2; ++mt)
#pragma unroll
            for (int nt = 0; nt < 4; ++nt)
                acc[mt][nt] = __builtin_amdgcn_mfma_f32_16x16x32_bf16(
                    af[mt], bfr[nt], acc[mt][nt], 0, 0, 0);
    }
#pragma unroll
    for (int nt = 0; nt < 4; ++nt) {
        const int cn = w * 64 + nt * 16 + lr;
        const float bv = b_out[cn];
#pragma unroll
        for (int mt = 0; mt < 2; ++mt)
#pragma unroll
            for (int r4 = 0; r4 < 4; ++r4)
                out[(row0 + mt * 16 + r0 + r4) * 256 + cn] = acc[mt][nt][r4] + bv;
    }
}

// ---------------------------------------------------------------------------
extern "C" void kernel_launch(void* const* d_in, const int* in_sizes, int n_in,
                              void* d_out, int out_size, void* d_ws, size_t ws_size,
                              hipStream_t stream)
{
    const float* x      = (const float*)d_in[0];
    const float* W_in   = (const float*)d_in[1];
    const float* b_in   = (const float*)d_in[2];
    const float* conv_w = (const float*)d_in[3];
    const float* conv_b = (const float*)d_in[4];
    const float* ln_g   = (const float*)d_in[5];
    const float* ln_b   = (const float*)d_in[6];
    const float* W_off  = (const float*)d_in[7];
    const float* b_off  = (const float*)d_in[8];
    const float* W_mask = (const float*)d_in[9];
    const float* b_mask = (const float*)d_in[10];
    const float* W_out  = (const float*)d_in[11];
    const float* b_out  = (const float*)d_in[12];

    // ws layout (of 256 MiB):
    //   [16M, 32M)    x_proj bf16 [32768][256]
    //   [32M, +280K)  Wt_in (128K), Wt_out (128K), Wcomb (24K)
    //   [48M, +6.3M)  rec uint2 [32768*24]
    u16* xprojb = (u16*)((char*)d_ws + 16777216);
    char* wsb   = (char*)d_ws + 33554432;
    u16* Wt_in  = (u16*)(wsb);
    u16* Wt_out = (u16*)(wsb + 131072);
    u16* Wcombp = (u16*)(wsb + 262144);
    uint2* rec  = (uint2*)((char*)d_ws + 50331648);

    prep_w<<<304, 256, 0, stream>>>(W_in, W_out, W_off, W_mask, Wt_in, Wt_out, Wcombp);
    conv_feat_proj<<<512, 256, 0, stream>>>(x, conv_w, conv_b, ln_g, ln_b,
                                            Wcombp, b_off, b_mask, rec);
    gemm1<<<512, 256, 0, stream>>>(x, Wt_in, b_in, xprojb);
    gather_gemm<<<1024, 256, 0, stream>>>(rec, xprojb, Wt_out, b_out, (float*)d_out);
}

// Round 13
// 70.073 us; speedup vs baseline: 1.0487x; 1.0487x over previous
//
#include <hip/hip_runtime.h>
#include <math.h>

// Problem constants
constexpr int LL = 4096;
constexpr int CC = 256;
constexpr int MM = 32768;  // N*L rows

typedef unsigned int u32;
typedef unsigned short u16;
typedef __attribute__((ext_vector_type(8))) short bf16x8;
typedef __attribute__((ext_vector_type(4))) float f32x4;

__device__ __forceinline__ u16 f2b(float f) {   // RNE fp32->bf16
    u32 u = __float_as_uint(f);
    u32 r = (u + 0x7fffu + ((u >> 16) & 1u)) >> 16;
    return (u16)r;
}
__device__ __forceinline__ u32 pack2(float a, float b) {  // RNE pair
    return (u32)f2b(a) | ((u32)f2b(b) << 16);
}

// async global->LDS DMA, 16B per lane; LDS dest = wave-uniform base + lane*16
__device__ __forceinline__ void gl_lds16(const u16* g, u16* l) {
    __builtin_amdgcn_global_load_lds(
        (const __attribute__((address_space(1))) unsigned int*)g,
        (__attribute__((address_space(3))) unsigned int*)l, 16, 0, 0);
}

// ---------------------------------------------------------------------------
// conv_prep: blocks [0,8192): depthwise conv(K=3) + LayerNorm + exact GELU.
// XCD-aligned remap: dispatch d (XCD d%8) handles rows of sequence n = d%8,
// so xfeat panels are written by (and L2-resident on) XCD n — matching the
// proj phase's reader mapping. blocks [8192,8496): bf16 weight prep.
// ---------------------------------------------------------------------------
__global__ __launch_bounds__(256) void conv_prep(
    const float* __restrict__ x, const float* __restrict__ cw,
    const float* __restrict__ cbias, const float* __restrict__ lng,
    const float* __restrict__ lnb, u16* __restrict__ xf,
    const float* __restrict__ W_in, const float* __restrict__ W_out,
    const float* __restrict__ W_off, const float* __restrict__ W_mask,
    u16* __restrict__ Wt_in, u16* __restrict__ Wt_out, u16* __restrict__ Wcomb)
{
    const int bid = blockIdx.x;
    const int t = threadIdx.x;
    if (bid >= 8192) {
        const int b = bid - 8192;
        if (b < 256) {
            Wt_in[b * 256 + t]  = f2b(W_in[t * 256 + b]);
            Wt_out[b * 256 + t] = f2b(W_out[t * 256 + b]);
        } else {
            const int j = b - 256;  // 0..47
            const float v = (j < 24) ? W_off[t * 24 + j] : W_mask[t * 24 + (j - 24)];
            Wcomb[j * 256 + t] = f2b(v);
        }
        return;
    }

    // XCD-aligned block remap: i = (bid%8)*1024 + bid/8  (bijective on 8192)
    const int i = ((bid & 7) << 10) | (bid >> 3);

    const int wave = t >> 6;
    const int lane = t & 63;
    const int nl = (i << 2) + wave;
    const int l = nl & (LL - 1);
    const int c0 = lane << 2;
    const size_t base = (size_t)nl * CC + c0;

    float4 xc = *(const float4*)&x[base];
    float4 xm = make_float4(0.f, 0.f, 0.f, 0.f);
    float4 xp = make_float4(0.f, 0.f, 0.f, 0.f);
    if (l > 0)      xm = *(const float4*)&x[base - CC];
    if (l < LL - 1) xp = *(const float4*)&x[base + CC];

    float xmv[4] = {xm.x, xm.y, xm.z, xm.w};
    float xcv[4] = {xc.x, xc.y, xc.z, xc.w};
    float xpv[4] = {xp.x, xp.y, xp.z, xp.w};

    float y[4];
    float sum = 0.f, sq = 0.f;
#pragma unroll
    for (int j = 0; j < 4; ++j) {
        const int c = c0 + j;
        float v = fmaf(xmv[j], cw[c * 3 + 0],
                  fmaf(xcv[j], cw[c * 3 + 1],
                  fmaf(xpv[j], cw[c * 3 + 2], cbias[c])));
        y[j] = v;
        sum += v;
        sq  += v * v;
    }
#pragma unroll
    for (int off = 32; off > 0; off >>= 1) {
        sum += __shfl_xor(sum, off);
        sq  += __shfl_xor(sq, off);
    }
    const float mu  = sum * (1.f / CC);
    const float var = sq * (1.f / CC) - mu * mu;
    const float rs  = rsqrtf(var + 1e-6f);

    ushort4 o;
    float ov[4];
#pragma unroll
    for (int j = 0; j < 4; ++j) {
        const int c = c0 + j;
        const float tn = (y[j] - mu) * rs * lng[c] + lnb[c];
        ov[j] = 0.5f * tn * (1.f + erff(tn * 0.70710678118654752f));
    }
    o.x = f2b(ov[0]); o.y = f2b(ov[1]); o.z = f2b(ov[2]); o.w = f2b(ov[3]);
    *(ushort4*)&xf[base] = o;
}

// ---------------------------------------------------------------------------
// gemm1: x_proj = bf16(x) @ Wt_in^T + b_in (bf16 out), m97 structure:
// 128x128 tile, BK=32, 4 waves, double-buffered LDS. A reg-staged from fp32
// (load-early/write-late); B via global_load_lds. XCD swizzle: XCD k owns
// m-tiles [32k,+32) = sequence n=k -> xproj panel L2-resident on XCD k.
// ---------------------------------------------------------------------------
__global__ __launch_bounds__(256, 2) void gemm1(
    const float* __restrict__ x, const u16* __restrict__ Wt_in,
    const float* __restrict__ b_in, u16* __restrict__ xprojb)
{
    __shared__ u16 As[2][128 * 32];
    __shared__ u16 Bs[2][128 * 32];

    const int t = threadIdx.x;
    const int w = t >> 6, lane = t & 63;
    const int lr = lane & 15, lk = lane >> 4;
    const int wm = w >> 1, wn = w & 1;

    const int d = blockIdx.x;              // 0..511
    const int m_t = (d & 7) * 32 + (d >> 4);
    const int n_t = (d >> 3) & 1;
    const int m0 = m_t * 128, n0 = n_t * 128;

    const int srow = lane >> 2;
    const int scol = (lane & 3) * 8;       // k elements
    const int arow = t >> 1;
    const int akh = (t & 1) * 16;

    f32x4 acc[4][4];
#pragma unroll
    for (int i = 0; i < 4; ++i)
#pragma unroll
        for (int j = 0; j < 4; ++j) acc[i][j] = f32x4{0.f, 0.f, 0.f, 0.f};

    auto STAGE_B = [&](int buf, int kt) {
        const int k0 = kt * 32;
#pragma unroll
        for (int j = 0; j < 2; ++j) {
            const int rr = (w * 2 + j) * 16 + srow;
            gl_lds16(Wt_in + ((size_t)(n0 + rr) << 8) + k0 + scol,
                     &Bs[buf][0] + (w * 2 + j) * 512);
        }
    };
    const float* Abase = x + (size_t)(m0 + arow) * 256 + akh;

    {
        float4 f0 = *(const float4*)(Abase);
        float4 f1 = *(const float4*)(Abase + 4);
        float4 f2 = *(const float4*)(Abase + 8);
        float4 f3 = *(const float4*)(Abase + 12);
        STAGE_B(0, 0);
        u16* dst = &As[0][arow * 32 + akh];
        ((u32*)dst)[0] = pack2(f0.x, f0.y); ((u32*)dst)[1] = pack2(f0.z, f0.w);
        ((u32*)dst)[2] = pack2(f1.x, f1.y); ((u32*)dst)[3] = pack2(f1.z, f1.w);
        ((u32*)dst)[4] = pack2(f2.x, f2.y); ((u32*)dst)[5] = pack2(f2.z, f2.w);
        ((u32*)dst)[6] = pack2(f3.x, f3.y); ((u32*)dst)[7] = pack2(f3.z, f3.w);
    }

#pragma unroll
    for (int kt = 0; kt < 8; ++kt) {
        const int cur = kt & 1;
        __syncthreads();                    // stage of buf[cur] complete
        float4 f0, f1, f2, f3;
        if (kt < 7) {                       // issue next-tile loads EARLY
            const float* ap = Abase + (kt + 1) * 32;
            f0 = *(const float4*)(ap);
            f1 = *(const float4*)(ap + 4);
            f2 = *(const float4*)(ap + 8);
            f3 = *(const float4*)(ap + 12);
            STAGE_B(cur ^ 1, kt + 1);
        }
        bf16x8 af[4], bfr[4];
#pragma unroll
        for (int mt = 0; mt < 4; ++mt)
            af[mt] = *(const bf16x8*)&As[cur][(wm * 64 + mt * 16 + lr) * 32 + lk * 8];
#pragma unroll
        for (int nt = 0; nt < 4; ++nt)
            bfr[nt] = *(const bf16x8*)&Bs[cur][(wn * 64 + nt * 16 + lr) * 32 + lk * 8];
#pragma unroll
        for (int mt = 0; mt < 4; ++mt)
#pragma unroll
            for (int nt = 0; nt < 4; ++nt)
                acc[mt][nt] = __builtin_amdgcn_mfma_f32_16x16x32_bf16(
                    af[mt], bfr[nt], acc[mt][nt], 0, 0, 0);
        if (kt < 7) {                       // write LATE (after MFMAs)
            u16* dst = &As[cur ^ 1][arow * 32 + akh];
            ((u32*)dst)[0] = pack2(f0.x, f0.y); ((u32*)dst)[1] = pack2(f0.z, f0.w);
            ((u32*)dst)[2] = pack2(f1.x, f1.y); ((u32*)dst)[3] = pack2(f1.z, f1.w);
            ((u32*)dst)[4] = pack2(f2.x, f2.y); ((u32*)dst)[5] = pack2(f2.z, f2.w);
            ((u32*)dst)[6] = pack2(f3.x, f3.y); ((u32*)dst)[7] = pack2(f3.z, f3.w);
        }
    }

    const int r0 = lk * 4;
#pragma unroll
    for (int nt = 0; nt < 4; ++nt) {
        const int cn = n0 + wn * 64 + nt * 16 + lr;
        const float bv = b_in[cn];
#pragma unroll
        for (int mt = 0; mt < 4; ++mt)
#pragma unroll
            for (int r4 = 0; r4 < 4; ++r4)
                xprojb[(size_t)(m0 + wm * 64 + mt * 16 + r0 + r4) * 256 + cn] =
                    f2b(acc[mt][nt][r4] + bv);
    }
}

// ---------------------------------------------------------------------------
// offmask_gemm: fused { offset/mask MFMA projection + softmax + bilinear
// gather -> LDS } + { final GEMM sampled@W_out + b_out -> fp32 out }.
// 64-row blocks (512), 256 thr, LDS 44KB. XCD-aligned remap: dispatch d
// (XCD d%8) handles row-block blk = (d%8)*64 + d/8 -> sequence n = d%8,
// whose xfeat/xproj panels sit in XCD d%8's L2 (written there by conv/gemm1).
// ---------------------------------------------------------------------------
__global__ __launch_bounds__(256, 3) void offmask_gemm(
    const u16* __restrict__ xfeatb, const u16* __restrict__ xprojb,
    const u16* __restrict__ Wcomb, const float* __restrict__ boff,
    const float* __restrict__ bmask, const u16* __restrict__ Wt_out,
    const float* __restrict__ b_out, float* __restrict__ out)
{
    __shared__ __align__(16) char s_mem[32768];   // logit then sampled (union)
    __shared__ uint2 s_pack[512 * 3];             // {fp16 a|b, u16 i0|i1} 12KB
    float* logit = (float*)s_mem;                 // [64][50]

    const int t = threadIdx.x;
    const int w = t >> 6, lane = t & 63;
    const int lr = lane & 15, lk8 = (lane >> 4) * 8;
    const int r0 = (lane >> 4) * 4;
    // XCD-aligned remap: blk = (d%8)*64 + d/8  (bijective on 512)
    const int d = blockIdx.x;
    const int blk = ((d & 7) << 6) | (d >> 3);
    const size_t row0 = (size_t)blk * 64;

    // --- Phase 1: projection MFMA -> logits (48 cols per row)
    f32x4 pacc[3];
#pragma unroll
    for (int ct = 0; ct < 3; ++ct) pacc[ct] = f32x4{0.f, 0.f, 0.f, 0.f};
    const u16* fbase = xfeatb + (row0 + w * 16 + lr) * 256;
#pragma unroll
    for (int ks = 0; ks < 8; ++ks) {
        const int ke = ks * 32 + lk8;
        bf16x8 a = *(const bf16x8*)(fbase + ke);
#pragma unroll
        for (int ct = 0; ct < 3; ++ct) {
            bf16x8 bfr = *(const bf16x8*)(Wcomb + (size_t)(ct * 16 + lr) * 256 + ke);
            pacc[ct] = __builtin_amdgcn_mfma_f32_16x16x32_bf16(a, bfr, pacc[ct], 0, 0, 0);
        }
    }
#pragma unroll
    for (int ct = 0; ct < 3; ++ct) {
        const int j = ct * 16 + lr;
        const float bj = (j < 24) ? boff[j] : bmask[j - 24];
#pragma unroll
        for (int r4 = 0; r4 < 4; ++r4)
            logit[(w * 16 + r0 + r4) * 50 + j] = pacc[ct][r4] + bj;
    }
    __syncthreads();

    // --- Phase 2: softmax over K + locations (2 (row,g) pairs per thread)
#pragma unroll
    for (int pi = 0; pi < 2; ++pi) {
        const int pp = pi * 256 + t;        // 0..511
        const int rw = pp >> 3, g = pp & 7;
        const float* lp = &logit[rw * 50];
        const float m0v = lp[24 + g * 3 + 0];
        const float m1v = lp[24 + g * 3 + 1];
        const float m2v = lp[24 + g * 3 + 2];
        const float mx = fmaxf(m0v, fmaxf(m1v, m2v));
        const float e0 = expf(m0v - mx), e1 = expf(m1v - mx), e2 = expf(m2v - mx);
        const float inv = 1.f / (e0 + e1 + e2);
        const float msk[3] = {e0 * inv, e1 * inv, e2 * inv};
        const float lf = (float)((blk & 63) * 64 + rw);
#pragma unroll
        for (int k = 0; k < 3; ++k) {
            const float loc = lf + (float)(k - 1) + lp[g * 3 + k];
            float r = fmodf(loc, (float)LL);
            if (r < 0.f) r += (float)LL;
            const float f0 = floorf(r);
            int i0 = (int)f0;
            i0 = i0 < 0 ? 0 : (i0 > LL - 1 ? LL - 1 : i0);
            const int i1 = i0 + 1;
            const float w1 = r - f0;
            const bool valid = (i1 < LL);
            union { u32 uw; _Float16 h[2]; } uh;
            uh.h[0] = (_Float16)(msk[k] * (1.f - w1));
            uh.h[1] = (_Float16)(valid ? msk[k] * w1 : 0.f);
            const u32 ij = (u32)i0 | ((u32)(valid ? i1 : 0) << 16);
            s_pack[pp * 3 + k] = make_uint2(uh.uw, ij);
        }
    }
    __syncthreads();   // logit reads done; s_mem reusable as sampled tile

    // --- Phase 3: gather-accumulate -> sampled bf16 tile in LDS (swizzled).
    // 8 row-groups x 32 channel-octs; uint4 loads (8 chans/thread).
    {
        const int ig = t >> 5, tc = t & 31;
        const int c0 = tc * 8, g4 = tc >> 2;
        const u16* xpn = xprojb + (size_t)(blk >> 6) * LL * 256;
        const int ibeg = ig * 8;
#pragma unroll 2
        for (int i = ibeg; i < ibeg + 8; ++i) {
            const int bidx = (i * 8 + g4) * 3;
            float v[8] = {0.f, 0.f, 0.f, 0.f, 0.f, 0.f, 0.f, 0.f};
#pragma unroll
            for (int k = 0; k < 3; ++k) {
                const uint2 pk = s_pack[bidx + k];
                union { u32 uw; _Float16 h[2]; } uh; uh.uw = pk.x;
                const float wa = (float)uh.h[0], wb = (float)uh.h[1];
                const int i0 = (int)(pk.y & 0xffffu), i1 = (int)(pk.y >> 16);
                uint4 ua = *(const uint4*)(xpn + (size_t)i0 * 256 + c0);
                uint4 ub = *(const uint4*)(xpn + (size_t)i1 * 256 + c0);
                const u32 au[4] = {ua.x, ua.y, ua.z, ua.w};
                const u32 bu[4] = {ub.x, ub.y, ub.z, ub.w};
#pragma unroll
                for (int j = 0; j < 4; ++j) {
                    v[2 * j]     = fmaf(wa, __uint_as_float(au[j] << 16),
                                   fmaf(wb, __uint_as_float(bu[j] << 16), v[2 * j]));
                    v[2 * j + 1] = fmaf(wa, __uint_as_float(au[j] & 0xffff0000u),
                                   fmaf(wb, __uint_as_float(bu[j] & 0xffff0000u), v[2 * j + 1]));
                }
            }
            uint4 wd;
            wd.x = pack2(v[0], v[1]); wd.y = pack2(v[2], v[3]);
            wd.z = pack2(v[4], v[5]); wd.w = pack2(v[6], v[7]);
            const int addr = (i * 512 + tc * 16) ^ ((i & 7) << 4);
            *(uint4*)(s_mem + addr) = wd;
        }
    }
    __syncthreads();

    // --- Phase 4: final GEMM 64x256 from LDS tile, wave w -> cols [w*64,+64)
    f32x4 acc[4][4];
#pragma unroll
    for (int i = 0; i < 4; ++i)
#pragma unroll
        for (int j = 0; j < 4; ++j) acc[i][j] = f32x4{0.f, 0.f, 0.f, 0.f};

    const u16* Bw = Wt_out + (size_t)(w * 64) * 256;
#pragma unroll
    for (int ks = 0; ks < 8; ++ks) {
        bf16x8 af[4], bfr[4];
#pragma unroll
        for (int mt = 0; mt < 4; ++mt) {
            const int rm = mt * 16 + lr;
            const int addr = (rm * 512 + ks * 64 + lk8 * 2) ^ ((rm & 7) << 4);
            af[mt] = *(const bf16x8*)(s_mem + addr);
        }
        const int ke = ks * 32 + lk8;
#pragma unroll
        for (int nt = 0; nt < 4; ++nt)
            bfr[nt] = *(const bf16x8*)(Bw + (size_t)(nt * 16 + lr) * 256 + ke);
#pragma unroll
        for (int mt = 0; mt < 4; ++mt)
#pragma unroll
            for (int nt = 0; nt < 4; ++nt)
                acc[mt][nt] = __builtin_amdgcn_mfma_f32_16x16x32_bf16(
                    af[mt], bfr[nt], acc[mt][nt], 0, 0, 0);
    }
#pragma unroll
    for (int nt = 0; nt < 4; ++nt) {
        const int cn = w * 64 + nt * 16 + lr;
        const float bv = b_out[cn];
#pragma unroll
        for (int mt = 0; mt < 4; ++mt)
#pragma unroll
            for (int r4 = 0; r4 < 4; ++r4)
                out[(row0 + mt * 16 + r0 + r4) * 256 + cn] = acc[mt][nt][r4] + bv;
    }
}

// ---------------------------------------------------------------------------
extern "C" void kernel_launch(void* const* d_in, const int* in_sizes, int n_in,
                              void* d_out, int out_size, void* d_ws, size_t ws_size,
                              hipStream_t stream)
{
    const float* x      = (const float*)d_in[0];
    const float* W_in   = (const float*)d_in[1];
    const float* b_in   = (const float*)d_in[2];
    const float* conv_w = (const float*)d_in[3];
    const float* conv_b = (const float*)d_in[4];
    const float* ln_g   = (const float*)d_in[5];
    const float* ln_b   = (const float*)d_in[6];
    const float* W_off  = (const float*)d_in[7];
    const float* b_off  = (const float*)d_in[8];
    const float* W_mask = (const float*)d_in[9];
    const float* b_mask = (const float*)d_in[10];
    const float* W_out  = (const float*)d_in[11];
    const float* b_out  = (const float*)d_in[12];

    // ws layout (~34 MB of 256 MiB):
    //   [0, 16M)      x_feat bf16 [32768][256]
    //   [16M, 32M)    x_proj bf16 [32768][256]
    //   [32M, ...)    Wt_in (128K), Wt_out (128K), Wcomb (24K)
    u16* xfeatb = (u16*)d_ws;
    u16* xprojb = (u16*)((char*)d_ws + 16777216);
    char* wsb   = (char*)d_ws + 33554432;
    u16* Wt_in  = (u16*)(wsb);
    u16* Wt_out = (u16*)(wsb + 131072);
    u16* Wcombp = (u16*)(wsb + 262144);

    conv_prep<<<8192 + 304, 256, 0, stream>>>(x, conv_w, conv_b, ln_g, ln_b, xfeatb,
                                              W_in, W_out, W_off, W_mask,
                                              Wt_in, Wt_out, Wcombp);
    gemm1<<<512, 256, 0, stream>>>(x, Wt_in, b_in, xprojb);
    offmask_gemm<<<512, 256, 0, stream>>>(xfeatb, xprojb, Wcombp, b_off, b_mask,
                                          Wt_out, b_out, (float*)d_out);
}